// Round 3
// baseline (62.750 us; speedup 1.0000x reference)
//
#include <hip/hip_runtime.h>

// B=256, T=256, D=384, HD=64
typedef __attribute__((ext_vector_type(8))) short bf16x8;
typedef __attribute__((ext_vector_type(4))) float f32x4;

__device__ inline unsigned short f2bf(float f) {
    unsigned u = __float_as_uint(f);
    return (unsigned short)((u + 0x7fffu + ((u >> 16) & 1u)) >> 16);
}

// ---------------------------------------------------------------------------
// Kernel 0: concatenate + convert W = [Wq;Wk;Wv] (192x384 f32) -> bf16
// ---------------------------------------------------------------------------
__global__ void wconv(const float* __restrict__ Wq, const float* __restrict__ Wk,
                      const float* __restrict__ Wv, short* __restrict__ Wcat) {
    int i = blockIdx.x * 256 + threadIdx.x;
    if (i >= 192 * 384) return;
    int row = i / 384;
    int col = i - row * 384;
    const float* src = row < 64 ? (Wq + row * 384)
                     : row < 128 ? (Wk + (row - 64) * 384)
                                 : (Wv + (row - 128) * 384);
    Wcat[i] = (short)f2bf(src[col]);
}

// ---------------------------------------------------------------------------
// Fused kernel: block = 1 batch (grid 256 = 1 block/CU), 8 waves (512 thr).
// Phase 1 (proj): C[256,192] = bf16(x_b) @ Wcat^T via mfma_16x16x32_bf16.
//   Waves 2Mx... wave layout: wm=(wv>>1)*64 rows, wn=(wv&1)*96 cols.
//   A-frags straight from global x (f32->bf16 in reg, depth-1 prefetch),
//   B-frags straight from Wcat (bf16, L2-hot). NO staging, NO barriers.
//   Epilogue scatters acc into LDS: Q,K row-major stride 72 (2-way = free),
//   V transposed [64][264] with XOR swizzle ((h>>3)&7)<<3 (R2-verified).
// Phase 2 (attn): R2-verified causal online-softmax MFMA attention, Q from
//   LDS. Wave w owns q-tiles 16w and 240-16w: exactly 9 kv-tiles each.
// ---------------------------------------------------------------------------
__global__ __launch_bounds__(512, 2) void fused_attn(
    const float* __restrict__ x, const short* __restrict__ Wcat,
    float* __restrict__ out) {
    __shared__ short Qlds[256 * 72];
    __shared__ short Ksh[256 * 72];
    __shared__ short Vt[64 * 264];
    __shared__ short Pb[8][16 * 40];

    const int tid = threadIdx.x;
    const int wv = tid >> 6, lane = tid & 63;
    const int g = lane >> 4, c = lane & 15;
    const int wm = (wv >> 1) * 64, wn = (wv & 1) * 96;
    const int b = blockIdx.x;

    // ---------------- Phase 1: QKV projection ----------------
    const float* xA[4];
#pragma unroll
    for (int mi = 0; mi < 4; ++mi)
        xA[mi] = x + ((size_t)b * 256 + wm + 16 * mi + c) * 384 + g * 8;
    const short* Bp[6];
#pragma unroll
    for (int nj = 0; nj < 6; ++nj)
        Bp[nj] = Wcat + (wn + 16 * nj + c) * 384 + g * 8;

    f32x4 acc[4][6];
#pragma unroll
    for (int i = 0; i < 4; ++i)
#pragma unroll
        for (int j = 0; j < 6; ++j) acc[i][j] = (f32x4){0.f, 0.f, 0.f, 0.f};

    float4 pa[4][2];
#pragma unroll
    for (int mi = 0; mi < 4; ++mi) {
        pa[mi][0] = *(const float4*)(xA[mi] + 0);
        pa[mi][1] = *(const float4*)(xA[mi] + 4);
    }

    for (int s = 0; s < 12; ++s) {
        const int kn = (s < 11 ? s + 1 : 11) * 32;
        float4 na[4][2];
#pragma unroll
        for (int mi = 0; mi < 4; ++mi) {      // prefetch next k-step (HBM)
            na[mi][0] = *(const float4*)(xA[mi] + kn + 0);
            na[mi][1] = *(const float4*)(xA[mi] + kn + 4);
        }
        bf16x8 bfr[6];
#pragma unroll
        for (int nj = 0; nj < 6; ++nj)        // B just-in-time (L2-hot)
            bfr[nj] = *(const bf16x8*)(Bp[nj] + s * 32);
        bf16x8 af[4];
#pragma unroll
        for (int mi = 0; mi < 4; ++mi) {
            bf16x8 t;
            t[0] = (short)f2bf(pa[mi][0].x); t[1] = (short)f2bf(pa[mi][0].y);
            t[2] = (short)f2bf(pa[mi][0].z); t[3] = (short)f2bf(pa[mi][0].w);
            t[4] = (short)f2bf(pa[mi][1].x); t[5] = (short)f2bf(pa[mi][1].y);
            t[6] = (short)f2bf(pa[mi][1].z); t[7] = (short)f2bf(pa[mi][1].w);
            af[mi] = t;
        }
#pragma unroll
        for (int mi = 0; mi < 4; ++mi)
#pragma unroll
            for (int nj = 0; nj < 6; ++nj)
                acc[mi][nj] = __builtin_amdgcn_mfma_f32_16x16x32_bf16(
                    af[mi], bfr[nj], acc[mi][nj], 0, 0, 0);
#pragma unroll
        for (int mi = 0; mi < 4; ++mi) {
            pa[mi][0] = na[mi][0];
            pa[mi][1] = na[mi][1];
        }
    }

    // epilogue: acc -> LDS.  C/D layout: col = c, row = 4g + r (verified).
#pragma unroll
    for (int mi = 0; mi < 4; ++mi) {
#pragma unroll
        for (int nj = 0; nj < 6; ++nj) {
            const int colb = wn + 16 * nj;          // wave-uniform
            const int row = wm + 16 * mi + 4 * g;
            if (colb < 64) {
#pragma unroll
                for (int r = 0; r < 4; ++r)
                    Qlds[(row + r) * 72 + colb + c] = (short)f2bf(acc[mi][nj][r]);
            } else if (colb < 128) {
#pragma unroll
                for (int r = 0; r < 4; ++r)
                    Ksh[(row + r) * 72 + (colb - 64) + c] = (short)f2bf(acc[mi][nj][r]);
            } else {
                const int h = colb - 128 + c;
                const int swz = ((h >> 3) & 7) << 3;
#pragma unroll
                for (int r = 0; r < 4; ++r)
                    Vt[(h * 264 + row + r) ^ swz] = (short)f2bf(acc[mi][nj][r]);
            }
        }
    }
    __syncthreads();

    // ---------------- Phase 2: causal attention ----------------
    for (int half = 0; half < 2; ++half) {
        const int q0 = (half == 0) ? 16 * wv : 240 - 16 * wv;
        bf16x8 qf0 = *(const bf16x8*)&Qlds[(q0 + c) * 72 + g * 8];
        bf16x8 qf1 = *(const bf16x8*)&Qlds[(q0 + c) * 72 + 32 + g * 8];
        f32x4 o[4];
#pragma unroll
        for (int nj = 0; nj < 4; ++nj) o[nj] = (f32x4){0.f, 0.f, 0.f, 0.f};
        float m[4] = {-INFINITY, -INFINITY, -INFINITY, -INFINITY};
        float ls[4] = {0.f, 0.f, 0.f, 0.f};
        const int jmax = (q0 + 15) >> 5;

        for (int j = 0; j <= jmax; ++j) {
            f32x4 s0 = {0.f, 0.f, 0.f, 0.f}, s1 = {0.f, 0.f, 0.f, 0.f};
            {
                bf16x8 kf;
                kf = *(const bf16x8*)&Ksh[(32 * j + c) * 72 + g * 8];
                s0 = __builtin_amdgcn_mfma_f32_16x16x32_bf16(qf0, kf, s0, 0, 0, 0);
                kf = *(const bf16x8*)&Ksh[(32 * j + c) * 72 + 32 + g * 8];
                s0 = __builtin_amdgcn_mfma_f32_16x16x32_bf16(qf1, kf, s0, 0, 0, 0);
                kf = *(const bf16x8*)&Ksh[(32 * j + 16 + c) * 72 + g * 8];
                s1 = __builtin_amdgcn_mfma_f32_16x16x32_bf16(qf0, kf, s1, 0, 0, 0);
                kf = *(const bf16x8*)&Ksh[(32 * j + 16 + c) * 72 + 32 + g * 8];
                s1 = __builtin_amdgcn_mfma_f32_16x16x32_bf16(qf1, kf, s1, 0, 0, 0);
            }
            float t0[4], t1[4];
#pragma unroll
            for (int r = 0; r < 4; ++r) {
                t0[r] = s0[r] * 0.125f;
                t1[r] = s1[r] * 0.125f;
            }
            if (j == jmax) {   // wave-uniform: diagonal tile, causal mask
                int q = q0 + 4 * g;
#pragma unroll
                for (int r = 0; r < 4; ++r) {
                    if (32 * j + c > q + r) t0[r] = -INFINITY;
                    if (32 * j + 16 + c > q + r) t1[r] = -INFINITY;
                }
            }
            float corr[4], p0[4], p1[4];
#pragma unroll
            for (int r = 0; r < 4; ++r) {
                float v = fmaxf(t0[r], t1[r]);
#pragma unroll
                for (int off = 1; off < 16; off <<= 1) v = fmaxf(v, __shfl_xor(v, off, 16));
                float mn = fmaxf(m[r], v);
                corr[r] = __expf(m[r] - mn);   // first tile: exp(-inf)=0
                m[r] = mn;
                p0[r] = __expf(t0[r] - mn);
                p1[r] = __expf(t1[r] - mn);
                float rs = p0[r] + p1[r];
#pragma unroll
                for (int off = 1; off < 16; off <<= 1) rs += __shfl_xor(rs, off, 16);
                ls[r] = ls[r] * corr[r] + rs;
            }
#pragma unroll
            for (int nj = 0; nj < 4; ++nj) {
                f32x4 t = o[nj];
                t[0] *= corr[0]; t[1] *= corr[1]; t[2] *= corr[2]; t[3] *= corr[3];
                o[nj] = t;
            }
            // P -> LDS (C/D rows) -> A-frag read (same-wave RAW, in-order LDS)
            short* pb = Pb[wv];
#pragma unroll
            for (int r = 0; r < 4; ++r) {
                pb[(4 * g + r) * 40 + c]      = (short)f2bf(p0[r]);
                pb[(4 * g + r) * 40 + 16 + c] = (short)f2bf(p1[r]);
            }
            bf16x8 pfa = *(const bf16x8*)&pb[c * 40 + g * 8];
#pragma unroll
            for (int nj = 0; nj < 4; ++nj) {
                int h = 16 * nj + c;
                int swz = ((2 * nj + (c >> 3)) & 7) << 3;
                bf16x8 vf = *(const bf16x8*)&Vt[(h * 264 + 32 * j + g * 8) ^ swz];
                o[nj] = __builtin_amdgcn_mfma_f32_16x16x32_bf16(pfa, vf, o[nj], 0, 0, 0);
            }
        }
        float inv[4];
#pragma unroll
        for (int r = 0; r < 4; ++r) inv[r] = 1.f / ls[r];
        float* ob = out + ((size_t)b * 256 + q0) * 64;
#pragma unroll
        for (int nj = 0; nj < 4; ++nj)
#pragma unroll
            for (int r = 0; r < 4; ++r)
                ob[(4 * g + r) * 64 + 16 * nj + c] = o[nj][r] * inv[r];
    }
}

// ---------------------------------------------------------------------------
extern "C" void kernel_launch(void* const* d_in, const int* in_sizes, int n_in,
                              void* d_out, int out_size, void* d_ws, size_t ws_size,
                              hipStream_t stream) {
    const float* x  = (const float*)d_in[0];
    const float* Wq = (const float*)d_in[1];
    const float* Wk = (const float*)d_in[2];
    const float* Wv = (const float*)d_in[3];
    float* out = (float*)d_out;

    short* Wcat = (short*)d_ws;   // 192*384 bf16 = 147 KB

    wconv<<<dim3(288), dim3(256), 0, stream>>>(Wq, Wk, Wv, Wcat);
    fused_attn<<<dim3(256), dim3(512), 0, stream>>>(x, Wcat, out);
}

// Round 4
// 50.370 us; speedup vs baseline: 1.2458x; 1.2458x over previous
//
#include <hip/hip_runtime.h>

// B=256, T=256, D=384, HD=64
typedef __attribute__((ext_vector_type(8))) short bf16x8;
typedef __attribute__((ext_vector_type(4))) float f32x4;

__device__ inline unsigned short f2bf(float f) {
    unsigned u = __float_as_uint(f);
    return (unsigned short)((u + 0x7fffu + ((u >> 16) & 1u)) >> 16);
}

// ---------------------------------------------------------------------------
// Kernel 0: concatenate + convert W = [Wq;Wk;Wv] (192x384 f32) -> bf16
// ---------------------------------------------------------------------------
__global__ void wconv(const float* __restrict__ Wq, const float* __restrict__ Wk,
                      const float* __restrict__ Wv, short* __restrict__ Wcat) {
    int i = blockIdx.x * 256 + threadIdx.x;
    if (i >= 192 * 384) return;
    int row = i / 384;
    int col = i - row * 384;
    const float* src = row < 64 ? (Wq + row * 384)
                     : row < 128 ? (Wk + (row - 64) * 384)
                                 : (Wv + (row - 128) * 384);
    Wcat[i] = (short)f2bf(src[col]);
}

// ---------------------------------------------------------------------------
// Fused kernel: block = 1 batch (grid 256 = 1 block/CU), 8 waves (512 thr).
// Phase 1 (proj): C[256,192] = bf16(x_b) @ Wcat^T via mfma_16x16x32_bf16.
//   x staged per 32-wide k-chunk as bf16 in LDS, DOUBLE-BUFFERED, reg-staged
//   (issue global loads for s+1 before MFMAs of s; convert+ds_write after).
//   Staging buffers overlay the Q/K LDS region (written only in epilogue).
//   Staging stride 40 shorts (80B): 16B-aligned b128, uniform 8 touches/bank.
//   B-frags from Wcat (L2-hot), prefetched one step ahead in registers.
// Phase 2 (attn): R2/R3-verified causal online-softmax MFMA attention.
//   Q,K row-major stride 72; V transposed [64][264] XOR-swizzled.
// ---------------------------------------------------------------------------
__global__ __launch_bounds__(512, 2) void fused_attn(
    const float* __restrict__ x, const short* __restrict__ Wcat,
    float* __restrict__ out) {
    __shared__ short QK[2 * 256 * 72];     // union: staging 2x[256*40] | Q,K
    __shared__ short Vt[64 * 264];
    __shared__ short Pb[8][16 * 40];
    short* const Qlds = QK;
    short* const Ksh  = QK + 256 * 72;
    constexpr int STR = 40;                // staging row stride (shorts)

    const int tid = threadIdx.x;
    const int wv = tid >> 6, lane = tid & 63;
    const int g = lane >> 4, c = lane & 15;
    const int wm = (wv >> 1) * 64, wn = (wv & 1) * 96;
    const int b = blockIdx.x;

    // ---------------- Phase 1: QKV projection ----------------
    // staging mapping: thread -> (row, 16-col half) of the 256x32 k-chunk
    const int sr = tid >> 1;
    const int sc = (tid & 1) * 16;
    const float* gxb = x + ((size_t)b * 256 + sr) * 384 + sc;
    short* const sw0 = &QK[sr * STR + sc];
    short* const sw1 = &QK[256 * STR + sr * STR + sc];

    const short* Bp[6];
#pragma unroll
    for (int nj = 0; nj < 6; ++nj)
        Bp[nj] = Wcat + (wn + 16 * nj + c) * 384 + g * 8;

    f32x4 acc[4][6];
#pragma unroll
    for (int i = 0; i < 4; ++i)
#pragma unroll
        for (int j = 0; j < 6; ++j) acc[i][j] = (f32x4){0.f, 0.f, 0.f, 0.f};

    // prologue: stage k-chunk 0 into buf0; B frags for s=0
    {
        float4 a0 = *(const float4*)(gxb + 0);
        float4 a1 = *(const float4*)(gxb + 4);
        float4 a2 = *(const float4*)(gxb + 8);
        float4 a3 = *(const float4*)(gxb + 12);
        bf16x8 w0, w1;
        w0[0] = (short)f2bf(a0.x); w0[1] = (short)f2bf(a0.y);
        w0[2] = (short)f2bf(a0.z); w0[3] = (short)f2bf(a0.w);
        w0[4] = (short)f2bf(a1.x); w0[5] = (short)f2bf(a1.y);
        w0[6] = (short)f2bf(a1.z); w0[7] = (short)f2bf(a1.w);
        w1[0] = (short)f2bf(a2.x); w1[1] = (short)f2bf(a2.y);
        w1[2] = (short)f2bf(a2.z); w1[3] = (short)f2bf(a2.w);
        w1[4] = (short)f2bf(a3.x); w1[5] = (short)f2bf(a3.y);
        w1[6] = (short)f2bf(a3.z); w1[7] = (short)f2bf(a3.w);
        *(bf16x8*)sw0 = w0;
        *(bf16x8*)(sw0 + 8) = w1;
    }
    bf16x8 bfr[6];
#pragma unroll
    for (int nj = 0; nj < 6; ++nj) bfr[nj] = *(const bf16x8*)(Bp[nj]);
    __syncthreads();

    for (int s = 0; s < 12; ++s) {
        // issue next-step loads EARLY (T14): x from HBM/L3, W from L2
        float4 n0, n1, n2, n3;
        bf16x8 bn[6];
        if (s < 11) {
            const float* gp = gxb + (s + 1) * 32;
            n0 = *(const float4*)(gp + 0);
            n1 = *(const float4*)(gp + 4);
            n2 = *(const float4*)(gp + 8);
            n3 = *(const float4*)(gp + 12);
#pragma unroll
            for (int nj = 0; nj < 6; ++nj)
                bn[nj] = *(const bf16x8*)(Bp[nj] + (s + 1) * 32);
        }
        // A-frags from current staging buffer (single b128 each)
        const short* sb = QK + (s & 1) * (256 * STR);
        bf16x8 af[4];
#pragma unroll
        for (int mi = 0; mi < 4; ++mi)
            af[mi] = *(const bf16x8*)&sb[(wm + 16 * mi + c) * STR + g * 8];
#pragma unroll
        for (int mi = 0; mi < 4; ++mi)
#pragma unroll
            for (int nj = 0; nj < 6; ++nj)
                acc[mi][nj] = __builtin_amdgcn_mfma_f32_16x16x32_bf16(
                    af[mi], bfr[nj], acc[mi][nj], 0, 0, 0);
        // write-late: convert + ds_write s+1 into the other buffer
        if (s < 11) {
            short* swn = ((s + 1) & 1) ? sw1 : sw0;
            bf16x8 w0, w1;
            w0[0] = (short)f2bf(n0.x); w0[1] = (short)f2bf(n0.y);
            w0[2] = (short)f2bf(n0.z); w0[3] = (short)f2bf(n0.w);
            w0[4] = (short)f2bf(n1.x); w0[5] = (short)f2bf(n1.y);
            w0[6] = (short)f2bf(n1.z); w0[7] = (short)f2bf(n1.w);
            w1[0] = (short)f2bf(n2.x); w1[1] = (short)f2bf(n2.y);
            w1[2] = (short)f2bf(n2.z); w1[3] = (short)f2bf(n2.w);
            w1[4] = (short)f2bf(n3.x); w1[5] = (short)f2bf(n3.y);
            w1[6] = (short)f2bf(n3.z); w1[7] = (short)f2bf(n3.w);
            *(bf16x8*)swn = w0;
            *(bf16x8*)(swn + 8) = w1;
#pragma unroll
            for (int nj = 0; nj < 6; ++nj) bfr[nj] = bn[nj];
        }
        __syncthreads();
    }

    // epilogue: acc -> LDS.  C/D layout: col = c, row = 4g + r (verified).
    // (loop's final barrier guarantees all staging reads are done)
#pragma unroll
    for (int mi = 0; mi < 4; ++mi) {
#pragma unroll
        for (int nj = 0; nj < 6; ++nj) {
            const int colb = wn + 16 * nj;          // wave-uniform
            const int row = wm + 16 * mi + 4 * g;
            if (colb < 64) {
#pragma unroll
                for (int r = 0; r < 4; ++r)
                    Qlds[(row + r) * 72 + colb + c] = (short)f2bf(acc[mi][nj][r]);
            } else if (colb < 128) {
#pragma unroll
                for (int r = 0; r < 4; ++r)
                    Ksh[(row + r) * 72 + (colb - 64) + c] = (short)f2bf(acc[mi][nj][r]);
            } else {
                const int h = colb - 128 + c;
                const int swz = ((h >> 3) & 7) << 3;
#pragma unroll
                for (int r = 0; r < 4; ++r)
                    Vt[(h * 264 + row + r) ^ swz] = (short)f2bf(acc[mi][nj][r]);
            }
        }
    }
    __syncthreads();

    // ---------------- Phase 2: causal attention ----------------
    for (int half = 0; half < 2; ++half) {
        const int q0 = (half == 0) ? 16 * wv : 240 - 16 * wv;
        bf16x8 qf0 = *(const bf16x8*)&Qlds[(q0 + c) * 72 + g * 8];
        bf16x8 qf1 = *(const bf16x8*)&Qlds[(q0 + c) * 72 + 32 + g * 8];
        f32x4 o[4];
#pragma unroll
        for (int nj = 0; nj < 4; ++nj) o[nj] = (f32x4){0.f, 0.f, 0.f, 0.f};
        float m[4] = {-INFINITY, -INFINITY, -INFINITY, -INFINITY};
        float ls[4] = {0.f, 0.f, 0.f, 0.f};
        const int jmax = (q0 + 15) >> 5;

        for (int j = 0; j <= jmax; ++j) {
            f32x4 s0 = {0.f, 0.f, 0.f, 0.f}, s1 = {0.f, 0.f, 0.f, 0.f};
            {
                bf16x8 kf;
                kf = *(const bf16x8*)&Ksh[(32 * j + c) * 72 + g * 8];
                s0 = __builtin_amdgcn_mfma_f32_16x16x32_bf16(qf0, kf, s0, 0, 0, 0);
                kf = *(const bf16x8*)&Ksh[(32 * j + c) * 72 + 32 + g * 8];
                s0 = __builtin_amdgcn_mfma_f32_16x16x32_bf16(qf1, kf, s0, 0, 0, 0);
                kf = *(const bf16x8*)&Ksh[(32 * j + 16 + c) * 72 + g * 8];
                s1 = __builtin_amdgcn_mfma_f32_16x16x32_bf16(qf0, kf, s1, 0, 0, 0);
                kf = *(const bf16x8*)&Ksh[(32 * j + 16 + c) * 72 + 32 + g * 8];
                s1 = __builtin_amdgcn_mfma_f32_16x16x32_bf16(qf1, kf, s1, 0, 0, 0);
            }
            float t0[4], t1[4];
#pragma unroll
            for (int r = 0; r < 4; ++r) {
                t0[r] = s0[r] * 0.125f;
                t1[r] = s1[r] * 0.125f;
            }
            if (j == jmax) {   // wave-uniform: diagonal tile, causal mask
                int q = q0 + 4 * g;
#pragma unroll
                for (int r = 0; r < 4; ++r) {
                    if (32 * j + c > q + r) t0[r] = -INFINITY;
                    if (32 * j + 16 + c > q + r) t1[r] = -INFINITY;
                }
            }
            float corr[4], p0[4], p1[4];
#pragma unroll
            for (int r = 0; r < 4; ++r) {
                float v = fmaxf(t0[r], t1[r]);
#pragma unroll
                for (int off = 1; off < 16; off <<= 1) v = fmaxf(v, __shfl_xor(v, off, 16));
                float mn = fmaxf(m[r], v);
                corr[r] = __expf(m[r] - mn);   // first tile: exp(-inf)=0
                m[r] = mn;
                p0[r] = __expf(t0[r] - mn);
                p1[r] = __expf(t1[r] - mn);
                float rs = p0[r] + p1[r];
#pragma unroll
                for (int off = 1; off < 16; off <<= 1) rs += __shfl_xor(rs, off, 16);
                ls[r] = ls[r] * corr[r] + rs;
            }
#pragma unroll
            for (int nj = 0; nj < 4; ++nj) {
                f32x4 t = o[nj];
                t[0] *= corr[0]; t[1] *= corr[1]; t[2] *= corr[2]; t[3] *= corr[3];
                o[nj] = t;
            }
            // P -> LDS (C/D rows) -> A-frag read (same-wave RAW, in-order LDS)
            short* pb = Pb[wv];
#pragma unroll
            for (int r = 0; r < 4; ++r) {
                pb[(4 * g + r) * 40 + c]      = (short)f2bf(p0[r]);
                pb[(4 * g + r) * 40 + 16 + c] = (short)f2bf(p1[r]);
            }
            bf16x8 pfa = *(const bf16x8*)&pb[c * 40 + g * 8];
#pragma unroll
            for (int nj = 0; nj < 4; ++nj) {
                int h = 16 * nj + c;
                int swz = ((2 * nj + (c >> 3)) & 7) << 3;
                bf16x8 vf = *(const bf16x8*)&Vt[(h * 264 + 32 * j + g * 8) ^ swz];
                o[nj] = __builtin_amdgcn_mfma_f32_16x16x32_bf16(pfa, vf, o[nj], 0, 0, 0);
            }
        }
        float inv[4];
#pragma unroll
        for (int r = 0; r < 4; ++r) inv[r] = 1.f / ls[r];
        float* ob = out + ((size_t)b * 256 + q0) * 64;
#pragma unroll
        for (int nj = 0; nj < 4; ++nj)
#pragma unroll
            for (int r = 0; r < 4; ++r)
                ob[(4 * g + r) * 64 + 16 * nj + c] = o[nj][r] * inv[r];
    }
}

// ---------------------------------------------------------------------------
extern "C" void kernel_launch(void* const* d_in, const int* in_sizes, int n_in,
                              void* d_out, int out_size, void* d_ws, size_t ws_size,
                              hipStream_t stream) {
    const float* x  = (const float*)d_in[0];
    const float* Wq = (const float*)d_in[1];
    const float* Wk = (const float*)d_in[2];
    const float* Wv = (const float*)d_in[3];
    float* out = (float*)d_out;

    short* Wcat = (short*)d_ws;   // 192*384 bf16 = 147 KB

    wconv<<<dim3(288), dim3(256), 0, stream>>>(Wq, Wk, Wv, Wcat);
    fused_attn<<<dim3(256), dim3(512), 0, stream>>>(x, Wcat, out);
}

// Round 5
// 45.086 us; speedup vs baseline: 1.3918x; 1.1172x over previous
//
#include <hip/hip_runtime.h>

// B=256, T=256, D=384, HD=64
typedef __attribute__((ext_vector_type(8))) short bf16x8;
typedef __attribute__((ext_vector_type(4))) float f32x4;

__device__ inline unsigned short f2bf(float f) {
    unsigned u = __float_as_uint(f);
    return (unsigned short)((u + 0x7fffu + ((u >> 16) & 1u)) >> 16);
}

// ---------------------------------------------------------------------------
// Kernel 0: concatenate + convert W = [Wq;Wk;Wv] (192x384 f32) -> bf16
// ---------------------------------------------------------------------------
__global__ void wconv(const float* __restrict__ Wq, const float* __restrict__ Wk,
                      const float* __restrict__ Wv, short* __restrict__ Wcat) {
    int i = blockIdx.x * 256 + threadIdx.x;
    if (i >= 192 * 384) return;
    int row = i / 384;
    int col = i - row * 384;
    const float* src = row < 64 ? (Wq + row * 384)
                     : row < 128 ? (Wk + (row - 64) * 384)
                                 : (Wv + (row - 128) * 384);
    Wcat[i] = (short)f2bf(src[col]);
}

// ---------------------------------------------------------------------------
// Fused kernel: block = 1 batch (grid 256 = 1 block/CU), 8 waves (512 thr).
// Phase 1 (proj): C[256,192] = bf16(x_b) @ Wcat^T via mfma_16x16x32_bf16.
//   ALL global loads lane-contiguous (R4 was transaction-bound on scattered
//   row-gathers): x per k-step remapped thread<->flat-float4 (16 lines/instr),
//   W k-window (12 KB) staged per step with 8B/thread chunks (8 lanes/line).
//   Both staged bf16 in LDS, double-buffered, stride 40 shorts (2-way = free
//   on b128 frag reads). Row-gathers now happen in LDS via ds_read_b128.
//   One barrier per step; loads for s+1 issued before MFMAs of s (T14).
// Phase 2 (attn): R2/R3-verified causal online-softmax MFMA attention.
//   Q,K row-major stride 72; V transposed [64][264] XOR-swizzled.
// ---------------------------------------------------------------------------
__global__ __launch_bounds__(512, 2) void fused_attn(
    const float* __restrict__ x, const short* __restrict__ Wcat,
    float* __restrict__ out) {
    __shared__ short QK[2 * 256 * 72];     // union: x-staging 2x[256*40] | Q,K
    __shared__ short Vt[64 * 264];
    __shared__ short Wst[2 * 192 * 40];    // W k-window staging, double-buffered
    __shared__ short Pb[8][16 * 40];
    short* const Qlds = QK;
    short* const Ksh  = QK + 256 * 72;
    constexpr int STR = 40;                // staging row stride (shorts)

    const int tid = threadIdx.x;
    const int wv = tid >> 6, lane = tid & 63;
    const int g = lane >> 4, c = lane & 15;
    const int wm = (wv >> 1) * 64, wn = (wv & 1) * 96;
    const int b = blockIdx.x;

    // ---------------- Phase 1: QKV projection ----------------
    // coalesced staging mapping: flat j = tid + 512*r -> row j>>3, chunk tid&7
    const int srow = tid >> 3;             // 0..63 (+64*r)
    const int sc4  = tid & 7;              // 0..7
    const float* gx = x + ((size_t)b * 256 + srow) * 384 + sc4 * 4;
    const short* gw = Wcat + srow * 384 + sc4 * 4;

    f32x4 acc[4][6];
#pragma unroll
    for (int i = 0; i < 4; ++i)
#pragma unroll
        for (int j = 0; j < 6; ++j) acc[i][j] = (f32x4){0.f, 0.f, 0.f, 0.f};

    float4 xv[4];
    uint2  wv2[3];
    // prologue: load + stage k-chunk 0 into buf0
#pragma unroll
    for (int r2 = 0; r2 < 4; ++r2) xv[r2] = *(const float4*)(gx + r2 * 24576);
#pragma unroll
    for (int r2 = 0; r2 < 3; ++r2) wv2[r2] = *(const uint2*)(gw + r2 * 24576);
#pragma unroll
    for (int r2 = 0; r2 < 4; ++r2) {
        uint2 p;
        p.x = (unsigned)f2bf(xv[r2].x) | ((unsigned)f2bf(xv[r2].y) << 16);
        p.y = (unsigned)f2bf(xv[r2].z) | ((unsigned)f2bf(xv[r2].w) << 16);
        *(uint2*)&QK[(srow + 64 * r2) * STR + sc4 * 4] = p;
    }
#pragma unroll
    for (int r2 = 0; r2 < 3; ++r2)
        *(uint2*)&Wst[(srow + 64 * r2) * STR + sc4 * 4] = wv2[r2];
    __syncthreads();

    for (int s = 0; s < 12; ++s) {
        // issue next-step loads EARLY (coalesced; land during MFMAs)
        if (s < 11) {
#pragma unroll
            for (int r2 = 0; r2 < 4; ++r2)
                xv[r2] = *(const float4*)(gx + (s + 1) * 32 + r2 * 24576);
#pragma unroll
            for (int r2 = 0; r2 < 3; ++r2)
                wv2[r2] = *(const uint2*)(gw + (s + 1) * 32 + r2 * 24576);
        }
        // frags from current buffers (single b128 each, 2-way = free)
        const short* xb = QK + (s & 1) * (256 * STR);
        const short* wb = Wst + (s & 1) * (192 * STR);
        bf16x8 af[4], bfr[6];
#pragma unroll
        for (int mi = 0; mi < 4; ++mi)
            af[mi] = *(const bf16x8*)&xb[(wm + 16 * mi + c) * STR + g * 8];
#pragma unroll
        for (int nj = 0; nj < 6; ++nj)
            bfr[nj] = *(const bf16x8*)&wb[(wn + 16 * nj + c) * STR + g * 8];
#pragma unroll
        for (int mi = 0; mi < 4; ++mi)
#pragma unroll
            for (int nj = 0; nj < 6; ++nj)
                acc[mi][nj] = __builtin_amdgcn_mfma_f32_16x16x32_bf16(
                    af[mi], bfr[nj], acc[mi][nj], 0, 0, 0);
        // write-late into the other buffer (vmcnt wait lands here)
        if (s < 11) {
            short* xd = QK + ((s + 1) & 1) * (256 * STR);
            short* wd = Wst + ((s + 1) & 1) * (192 * STR);
#pragma unroll
            for (int r2 = 0; r2 < 4; ++r2) {
                uint2 p;
                p.x = (unsigned)f2bf(xv[r2].x) | ((unsigned)f2bf(xv[r2].y) << 16);
                p.y = (unsigned)f2bf(xv[r2].z) | ((unsigned)f2bf(xv[r2].w) << 16);
                *(uint2*)&xd[(srow + 64 * r2) * STR + sc4 * 4] = p;
            }
#pragma unroll
            for (int r2 = 0; r2 < 3; ++r2)
                *(uint2*)&wd[(srow + 64 * r2) * STR + sc4 * 4] = wv2[r2];
        }
        __syncthreads();
    }

    // epilogue: acc -> LDS.  C/D layout: col = c, row = 4g + r (verified).
    // (loop's final barrier guarantees all staging reads are done)
#pragma unroll
    for (int mi = 0; mi < 4; ++mi) {
#pragma unroll
        for (int nj = 0; nj < 6; ++nj) {
            const int colb = wn + 16 * nj;          // wave-uniform
            const int row = wm + 16 * mi + 4 * g;
            if (colb < 64) {
#pragma unroll
                for (int r = 0; r < 4; ++r)
                    Qlds[(row + r) * 72 + colb + c] = (short)f2bf(acc[mi][nj][r]);
            } else if (colb < 128) {
#pragma unroll
                for (int r = 0; r < 4; ++r)
                    Ksh[(row + r) * 72 + (colb - 64) + c] = (short)f2bf(acc[mi][nj][r]);
            } else {
                const int h = colb - 128 + c;
                const int swz = ((h >> 3) & 7) << 3;
#pragma unroll
                for (int r = 0; r < 4; ++r)
                    Vt[(h * 264 + row + r) ^ swz] = (short)f2bf(acc[mi][nj][r]);
            }
        }
    }
    __syncthreads();

    // ---------------- Phase 2: causal attention ----------------
    for (int half = 0; half < 2; ++half) {
        const int q0 = (half == 0) ? 16 * wv : 240 - 16 * wv;
        bf16x8 qf0 = *(const bf16x8*)&Qlds[(q0 + c) * 72 + g * 8];
        bf16x8 qf1 = *(const bf16x8*)&Qlds[(q0 + c) * 72 + 32 + g * 8];
        f32x4 o[4];
#pragma unroll
        for (int nj = 0; nj < 4; ++nj) o[nj] = (f32x4){0.f, 0.f, 0.f, 0.f};
        float m[4] = {-INFINITY, -INFINITY, -INFINITY, -INFINITY};
        float ls[4] = {0.f, 0.f, 0.f, 0.f};
        const int jmax = (q0 + 15) >> 5;

        for (int j = 0; j <= jmax; ++j) {
            f32x4 s0 = {0.f, 0.f, 0.f, 0.f}, s1 = {0.f, 0.f, 0.f, 0.f};
            {
                bf16x8 kf;
                kf = *(const bf16x8*)&Ksh[(32 * j + c) * 72 + g * 8];
                s0 = __builtin_amdgcn_mfma_f32_16x16x32_bf16(qf0, kf, s0, 0, 0, 0);
                kf = *(const bf16x8*)&Ksh[(32 * j + c) * 72 + 32 + g * 8];
                s0 = __builtin_amdgcn_mfma_f32_16x16x32_bf16(qf1, kf, s0, 0, 0, 0);
                kf = *(const bf16x8*)&Ksh[(32 * j + 16 + c) * 72 + g * 8];
                s1 = __builtin_amdgcn_mfma_f32_16x16x32_bf16(qf0, kf, s1, 0, 0, 0);
                kf = *(const bf16x8*)&Ksh[(32 * j + 16 + c) * 72 + 32 + g * 8];
                s1 = __builtin_amdgcn_mfma_f32_16x16x32_bf16(qf1, kf, s1, 0, 0, 0);
            }
            float t0[4], t1[4];
#pragma unroll
            for (int r = 0; r < 4; ++r) {
                t0[r] = s0[r] * 0.125f;
                t1[r] = s1[r] * 0.125f;
            }
            if (j == jmax) {   // wave-uniform: diagonal tile, causal mask
                int q = q0 + 4 * g;
#pragma unroll
                for (int r = 0; r < 4; ++r) {
                    if (32 * j + c > q + r) t0[r] = -INFINITY;
                    if (32 * j + 16 + c > q + r) t1[r] = -INFINITY;
                }
            }
            float corr[4], p0[4], p1[4];
#pragma unroll
            for (int r = 0; r < 4; ++r) {
                float v = fmaxf(t0[r], t1[r]);
#pragma unroll
                for (int off = 1; off < 16; off <<= 1) v = fmaxf(v, __shfl_xor(v, off, 16));
                float mn = fmaxf(m[r], v);
                corr[r] = __expf(m[r] - mn);   // first tile: exp(-inf)=0
                m[r] = mn;
                p0[r] = __expf(t0[r] - mn);
                p1[r] = __expf(t1[r] - mn);
                float rs = p0[r] + p1[r];
#pragma unroll
                for (int off = 1; off < 16; off <<= 1) rs += __shfl_xor(rs, off, 16);
                ls[r] = ls[r] * corr[r] + rs;
            }
#pragma unroll
            for (int nj = 0; nj < 4; ++nj) {
                f32x4 t = o[nj];
                t[0] *= corr[0]; t[1] *= corr[1]; t[2] *= corr[2]; t[3] *= corr[3];
                o[nj] = t;
            }
            // P -> LDS (C/D rows) -> A-frag read (same-wave RAW, in-order LDS)
            short* pb = Pb[wv];
#pragma unroll
            for (int r = 0; r < 4; ++r) {
                pb[(4 * g + r) * 40 + c]      = (short)f2bf(p0[r]);
                pb[(4 * g + r) * 40 + 16 + c] = (short)f2bf(p1[r]);
            }
            bf16x8 pfa = *(const bf16x8*)&pb[c * 40 + g * 8];
#pragma unroll
            for (int nj = 0; nj < 4; ++nj) {
                int h = 16 * nj + c;
                int swz = ((2 * nj + (c >> 3)) & 7) << 3;
                bf16x8 vf = *(const bf16x8*)&Vt[(h * 264 + 32 * j + g * 8) ^ swz];
                o[nj] = __builtin_amdgcn_mfma_f32_16x16x32_bf16(pfa, vf, o[nj], 0, 0, 0);
            }
        }
        float inv[4];
#pragma unroll
        for (int r = 0; r < 4; ++r) inv[r] = 1.f / ls[r];
        float* ob = out + ((size_t)b * 256 + q0) * 64;
#pragma unroll
        for (int nj = 0; nj < 4; ++nj)
#pragma unroll
            for (int r = 0; r < 4; ++r)
                ob[(4 * g + r) * 64 + 16 * nj + c] = o[nj][r] * inv[r];
    }
}

// ---------------------------------------------------------------------------
extern "C" void kernel_launch(void* const* d_in, const int* in_sizes, int n_in,
                              void* d_out, int out_size, void* d_ws, size_t ws_size,
                              hipStream_t stream) {
    const float* x  = (const float*)d_in[0];
    const float* Wq = (const float*)d_in[1];
    const float* Wk = (const float*)d_in[2];
    const float* Wv = (const float*)d_in[3];
    float* out = (float*)d_out;

    short* Wcat = (short*)d_ws;   // 192*384 bf16 = 147 KB

    wconv<<<dim3(288), dim3(256), 0, stream>>>(Wq, Wk, Wv, Wcat);
    fused_attn<<<dim3(256), dim3(512), 0, stream>>>(x, Wcat, out);
}